// Round 5
// baseline (42.369 us; speedup 1.0000x reference)
//
#include <hip/hip_runtime.h>
#include <hip/hip_bf16.h>

#define IN_F   4096
#define OUT_F  11008
#define BATCH  32
#define GROUP  128
#define NCHUNK 4
#define KCHUNK 1024                 // k covered per chunk per block

typedef __attribute__((ext_vector_type(8))) short  bf16x8;
typedef __attribute__((ext_vector_type(4))) float  f32x4;
typedef __attribute__((ext_vector_type(4))) int    i32x4;
typedef __attribute__((ext_vector_type(4))) float  float4v;

static __device__ __constant__ float NF4_LEVELS[16] = {
    -1.0f, -0.6961928009986877f, -0.5250730514526367f, -0.39491748809814453f,
    -0.28444138169288635f, -0.18477343022823334f, -0.09105003625154495f, 0.0f,
    0.07958029955625534f, 0.16093020141124725f, 0.24611230194568634f,
    0.33791524171829224f, 0.44070982933044434f, 0.5626170039176941f,
    0.7229568362236023f, 1.0f};

// ---------------------------------------------------------------------------
// Kernel 1: x f32 -> bf16 into workspace (exact 32768 elems = 32 blocks)
// ---------------------------------------------------------------------------
__global__ void prelude_kernel(const float* __restrict__ x,
                               __hip_bfloat16* __restrict__ xb) {
    int i = (blockIdx.x * 256 + threadIdx.x) * 4;
    float4v v = *reinterpret_cast<const float4v*>(x + i);
    ushort4 o;
    o.x = __builtin_bit_cast(unsigned short, __float2bfloat16(v.x));
    o.y = __builtin_bit_cast(unsigned short, __float2bfloat16(v.y));
    o.z = __builtin_bit_cast(unsigned short, __float2bfloat16(v.z));
    o.w = __builtin_bit_cast(unsigned short, __float2bfloat16(v.w));
    *reinterpret_cast<ushort4*>(reinterpret_cast<unsigned short*>(xb) + i) = o;
}

// ---------------------------------------------------------------------------
// Kernel 2: NF4 dequant + GEMM, LDS-staged packed stream, zero atomics.
//   Block: 16 out-rows x K=4096, 256 threads (4 waves). K in 4 chunks of 1024.
//   Staging (per chunk): wave w loads rows w*4..w*4+3 as CONTIGUOUS 1KB/instr
//   i32x4 loads (8 instrs), compacts 4 int32 -> 1 byte dword, ds_writes into
//   a permuted+swizzled buffer so readers use single ds_read_b128 per 128k.
//
//   Index math (per row, per chunk: 512 src int32 = 128 compacted dwords):
//     source dword j  <-> k-pairs [8j, 8j+8)  (j = w_r*32 + (ss*4+t)*4 + g)
//     reader wants dword d = w_r*32 + g*8 + ss*4 + t  (b128 = 4 steps)
//     perm: d = (j&96) | ((j&3)<<3) | ((j>>2)&7)
//     bank swizzle (bits 2-4 of dword index, within-row): idx ^= (row&7)<<2
//     -> writer ds_write_b32 conflict-free; reader b128 2 lanes/bank (free).
// ---------------------------------------------------------------------------
__global__ __launch_bounds__(256, 3) void nf4_gemm_kernel(
        const int*   __restrict__ packed,   // [OUT_F*IN_F/2] one byte per int32
        const float* __restrict__ scales,   // [OUT_F*IN_F/GROUP]
        const float* __restrict__ bias,     // [OUT_F]
        const __hip_bfloat16* __restrict__ xb,  // [BATCH][IN_F] bf16
        float* __restrict__ out)            // [BATCH][OUT_F]
{
    __shared__ unsigned tabu[256];       // byte -> packed bf16 level pair
    __shared__ unsigned sbuf[2][16 * 128];   // 2 x 8KB compacted nibble-codes
    __shared__ float    red[4][2][16][16];   // cross-wave reduction

    const int tid  = threadIdx.x;
    const int wave = tid >> 6;
    const int lane = tid & 63;
    const int col  = lane & 15;   // B: out-row in tile; A: batch row 0..15
    const int g    = lane >> 4;   // k subgroup 0..3

    {
        unsigned lo = __builtin_bit_cast(unsigned short, __float2bfloat16(NF4_LEVELS[tid & 15]));
        unsigned hi = __builtin_bit_cast(unsigned short, __float2bfloat16(NF4_LEVELS[(tid >> 4) & 15]));
        tabu[tid] = lo | (hi << 16);
    }

    const int n0 = blockIdx.x * 16;
    const int o  = n0 + col;

    const unsigned short* xs  = reinterpret_cast<const unsigned short*>(xb);
    const unsigned short* xr0 = xs + (size_t)col * IN_F;          // batch 0..15
    const unsigned short* xr1 = xs + (size_t)(col + 16) * IN_F;   // batch 16..31

    // ---- staging helpers (all indices compile-time after unroll) ----
    // chunk c: wave stages rows wave*4..+3; instr i covers half a row (64 dw)
    #define STAGE_LOAD(c, regs)                                                   \
        _Pragma("unroll")                                                         \
        for (int i = 0; i < 8; ++i) {                                             \
            int lin = i * 64 + lane;                                              \
            int rl  = lin >> 7;              /* row_local 0..3 */                 \
            int j   = lin & 127;             /* compacted dword in row-chunk */   \
            regs[i] = *reinterpret_cast<const i32x4*>(                            \
                packed + (size_t)(n0 + wave * 4 + rl) * (IN_F / 2)                \
                       + (c) * (KCHUNK / 2) + j * 4);                             \
        }

    #define STAGE_WRITE(c, regs)                                                  \
        _Pragma("unroll")                                                         \
        for (int i = 0; i < 8; ++i) {                                             \
            int lin = i * 64 + lane;                                              \
            int rl  = lin >> 7;                                                   \
            int j   = lin & 127;                                                  \
            int row = wave * 4 + rl;                                              \
            int d   = (j & 96) | ((j & 3) << 3) | ((j >> 2) & 7);                 \
            unsigned v = ((unsigned)(regs[i][0] & 255))                           \
                       | ((unsigned)(regs[i][1] & 255) << 8)                      \
                       | ((unsigned)(regs[i][2] & 255) << 16)                     \
                       | ((unsigned)(regs[i][3] & 255) << 24);                    \
            sbuf[(c) & 1][(row * 128 + d) ^ ((row & 7) << 2)] = v;                \
        }

    f32x4 acc0 = {0.f, 0.f, 0.f, 0.f};   // batch 0-15
    f32x4 acc1 = {0.f, 0.f, 0.f, 0.f};   // batch 16-31

    // prologue: stage chunk 0
    {
        i32x4 sregs[8];
        STAGE_LOAD(0, sregs)
        STAGE_WRITE(0, sregs)
    }
    __syncthreads();

    #pragma unroll
    for (int c = 0; c < NCHUNK; ++c) {
        i32x4 nregs[8];
        if (c < NCHUNK - 1) { STAGE_LOAD(c + 1, nregs) }   // issue early (T14)

        const unsigned* buf = sbuf[c & 1];
        const int kbase = c * KCHUNK + wave * 256;          // this wave's k slice
        const float sc0 = scales[o * (IN_F / GROUP) + (kbase >> 7)];
        const float sc1 = scales[o * (IN_F / GROUP) + (kbase >> 7) + 1];

        // B-code reads: one b128 per superstep (128 k each)
        const int ridx0 = (col * 128 + wave * 32 + g * 8 + 0) ^ ((col & 7) << 2);
        const int ridx1 = (col * 128 + wave * 32 + g * 8 + 4) ^ ((col & 7) << 2);
        i32x4 codes0 = *reinterpret_cast<const i32x4*>(&buf[ridx0]);
        i32x4 codes1 = *reinterpret_cast<const i32x4*>(&buf[ridx1]);

        // A fragments, both supersteps (prefetched; L2-resident)
        bf16x8 A0[8], A1[8];
        #pragma unroll
        for (int s = 0; s < 8; ++s) {
            int k = kbase + s * 32 + g * 8;
            A0[s] = *reinterpret_cast<const bf16x8*>(xr0 + k);
            A1[s] = *reinterpret_cast<const bf16x8*>(xr1 + k);
        }

        #pragma unroll
        for (int ss = 0; ss < 2; ++ss) {
            f32x4 t0 = {0.f, 0.f, 0.f, 0.f};
            f32x4 t1 = {0.f, 0.f, 0.f, 0.f};
            #pragma unroll
            for (int t = 0; t < 4; ++t) {
                unsigned code = (unsigned)((ss == 0) ? codes0[t] : codes1[t]);
                i32x4 bu;
                bu[0] = (int)tabu[code & 255u];
                bu[1] = (int)tabu[(code >> 8) & 255u];
                bu[2] = (int)tabu[(code >> 16) & 255u];
                bu[3] = (int)tabu[code >> 24];
                bf16x8 bfrag = __builtin_bit_cast(bf16x8, bu);
                t0 = __builtin_amdgcn_mfma_f32_16x16x32_bf16(A0[ss * 4 + t], bfrag, t0, 0, 0, 0);
                t1 = __builtin_amdgcn_mfma_f32_16x16x32_bf16(A1[ss * 4 + t], bfrag, t1, 0, 0, 0);
            }
            const float sc = (ss == 0) ? sc0 : sc1;
            #pragma unroll
            for (int j = 0; j < 4; ++j) {
                acc0[j] = fmaf(sc, t0[j], acc0[j]);
                acc1[j] = fmaf(sc, t1[j], acc1[j]);
            }
        }

        if (c < NCHUNK - 1) { STAGE_WRITE(c + 1, nregs) }   // write late
        __syncthreads();
    }

    // ---- cross-wave reduction + store (D: row=(lane>>4)*4+j, col=lane&15) ----
    #pragma unroll
    for (int j = 0; j < 4; ++j) {
        red[wave][0][g * 4 + j][col] = acc0[j];
        red[wave][1][g * 4 + j][col] = acc1[j];
    }
    __syncthreads();

    #pragma unroll
    for (int half = 0; half < 2; ++half) {
        int idx = half * 256 + tid;          // 0..511 outputs of this block
        int mt  = idx >> 8;
        int row = (idx >> 4) & 15;
        int cc  = idx & 15;
        float ssum = red[0][mt][row][cc] + red[1][mt][row][cc] +
                     red[2][mt][row][cc] + red[3][mt][row][cc];
        int b = mt * 16 + row;
        out[(size_t)b * OUT_F + (n0 + cc)] = ssum + bias[n0 + cc];
    }
}

// ---------------------------------------------------------------------------
extern "C" void kernel_launch(void* const* d_in, const int* in_sizes, int n_in,
                              void* d_out, int out_size, void* d_ws, size_t ws_size,
                              hipStream_t stream) {
    const float* x      = (const float*)d_in[0];
    const int*   packed = (const int*)d_in[1];
    const float* scales = (const float*)d_in[2];
    const float* bias   = (const float*)d_in[3];
    float* out = (float*)d_out;

    __hip_bfloat16* xb = (__hip_bfloat16*)d_ws;  // BATCH*IN_F*2 = 256 KB

    prelude_kernel<<<BATCH * IN_F / (256 * 4), 256, 0, stream>>>(x, xb);
    nf4_gemm_kernel<<<OUT_F / 16, 256, 0, stream>>>(packed, scales, bias, xb, out);
}

// Round 6
// 32.606 us; speedup vs baseline: 1.2994x; 1.2994x over previous
//
#include <hip/hip_runtime.h>
#include <hip/hip_bf16.h>

#define IN_F   4096
#define OUT_F  11008
#define BATCH  32
#define GROUP  128
#define KSPLIT 4
#define KBLK   (IN_F / KSPLIT)    // 1024 k per block
#define NTILE  64                 // out-rows per block
#define GRID_N (OUT_F / NTILE)    // 172
#define OUTSZ  (BATCH * OUT_F)    // 352256

typedef __attribute__((ext_vector_type(8))) short  bf16x8;
typedef __attribute__((ext_vector_type(4))) float  f32x4;
typedef __attribute__((ext_vector_type(4))) int    i32x4;

static __device__ __constant__ float NF4_LEVELS[16] = {
    -1.0f, -0.6961928009986877f, -0.5250730514526367f, -0.39491748809814453f,
    -0.28444138169288635f, -0.18477343022823334f, -0.09105003625154495f, 0.0f,
    0.07958029955625534f, 0.16093020141124725f, 0.24611230194568634f,
    0.33791524171829224f, 0.44070982933044434f, 0.5626170039176941f,
    0.7229568362236023f, 1.0f};

// ws layout (bytes): frag 262144 | sct 1409024 | part 5636096  (~7.3 MB)
#define WS_SCT_OFF  262144
#define WS_PART_OFF (262144 + 1409024)

// ---------------------------------------------------------------------------
// Prelude: (a) build A-fragment streams in MFMA order:
//   frag[st][kb][lane] (16B) = x[st*16+(lane&15)][kb*32+(lane>>4)*8 .. +8) bf16
//   -> gemm A-load is ONE contiguous 1KB wave-instruction.
// (b) transpose scales: sct[gr][o] = scales[o*32+gr] -> broadcast reads.
// grid = 64 + 1376 = 1440 blocks
// ---------------------------------------------------------------------------
__global__ void prelude_kernel(const float* __restrict__ x,
                               const float* __restrict__ scales,
                               unsigned short* __restrict__ frag,
                               float* __restrict__ sct) {
    const int bid = blockIdx.x, tid = threadIdx.x;
    if (bid < 64) {
        int T  = bid * 256 + tid;        // [0, 16384)
        int st = T >> 13;                // 0..1 (batch halves)
        int kb = (T >> 6) & 127;         // k-block of 32
        int l  = T & 63;                 // lane slot
        int row = st * 16 + (l & 15);
        int k0  = kb * 32 + (l >> 4) * 8;
        const float* src = x + (size_t)row * IN_F + k0;
        unsigned w[4];
        #pragma unroll
        for (int e = 0; e < 4; ++e) {
            unsigned lo = __builtin_bit_cast(unsigned short, __float2bfloat16(src[2 * e]));
            unsigned hi = __builtin_bit_cast(unsigned short, __float2bfloat16(src[2 * e + 1]));
            w[e] = lo | (hi << 16);
        }
        i32x4 v = { (int)w[0], (int)w[1], (int)w[2], (int)w[3] };
        *reinterpret_cast<i32x4*>(frag + ((size_t)st * 8192 + kb * 64 + l) * 8) = v;
    } else {
        int B2 = bid - 64;               // [0, 1376) = 32 groups x 43 blocks
        int gr = B2 / 43;
        int o  = (B2 % 43) * 256 + tid;  // [0, 11008)
        sct[gr * OUT_F + o] = scales[o * 32 + gr];
    }
}

// ---------------------------------------------------------------------------
// Main: grid (172, 4). Block = 64 out-rows x 1024 k, 256 thr (4 waves).
// Stage packed (contiguous 1KB loads) -> LDS nibble-codes with perm+swizzle:
//   per row-chunk of 128 compacted dwords, source j (=k/8) -> d =
//   (j&0x70)|((j&3)<<2)|((j>>2)&3); addr ^= (row&7)<<2.
//   Reader (wave w, strip st, half ss): ds_read_b128 at
//   row*128 + w*32 + ss*16 + g*4 (^swz) gives steps t=0..3.
// Waves split K (256 each), cover all 4 strips; cross-wave LDS reduce;
// plain stores to per-K-slice partial buffer.
// ---------------------------------------------------------------------------
__global__ __launch_bounds__(256) void nf4_gemm_kernel(
        const int* __restrict__ packed,
        const unsigned short* __restrict__ frag,
        const float* __restrict__ sct,
        float* __restrict__ part)
{
    __shared__ unsigned tabu[256];
    __shared__ unsigned ovl[8192];   // 32KB: codes, then reused as reduce buffer

    const int tid  = threadIdx.x;
    const int wave = tid >> 6;
    const int lane = tid & 63;
    const int col  = lane & 15;
    const int g    = lane >> 4;

    {
        unsigned lo = __builtin_bit_cast(unsigned short, __float2bfloat16(NF4_LEVELS[tid & 15]));
        unsigned hi = __builtin_bit_cast(unsigned short, __float2bfloat16(NF4_LEVELS[(tid >> 4) & 15]));
        tabu[tid] = lo | (hi << 16);
    }

    const int n0 = blockIdx.x * NTILE;
    const int k0 = blockIdx.y * KBLK;
    const int* psrc = packed + (size_t)(n0 + wave * 16) * (IN_F / 2) + (k0 >> 1);

    // ---- stage: wave stages its 16 rows; 2 rounds of 16 contiguous 1KB loads
    #pragma unroll
    for (int r = 0; r < 2; ++r) {
        i32x4 sr[16];
        #pragma unroll
        for (int ii = 0; ii < 16; ++ii) {
            int i = r * 16 + ii;
            int rl = i >> 1, half = i & 1;
            sr[ii] = *reinterpret_cast<const i32x4*>(
                psrc + (size_t)rl * (IN_F / 2) + half * 256 + lane * 4);
        }
        #pragma unroll
        for (int ii = 0; ii < 16; ++ii) {
            int i = r * 16 + ii;
            int rl = i >> 1, half = i & 1;
            int row = wave * 16 + rl;
            int j = half * 64 + lane;
            int d = (j & 0x70) | ((j & 3) << 2) | ((j >> 2) & 3);
            unsigned v = ((unsigned)(sr[ii][0] & 255))
                       | ((unsigned)(sr[ii][1] & 255) << 8)
                       | ((unsigned)(sr[ii][2] & 255) << 16)
                       | ((unsigned)(sr[ii][3] & 255) << 24);
            ovl[(row * 128 + d) ^ ((row & 7) << 2)] = v;
        }
    }
    __syncthreads();

    f32x4 acc[4][2];
    #pragma unroll
    for (int st = 0; st < 4; ++st)
        #pragma unroll
        for (int h = 0; h < 2; ++h)
            acc[st][h] = (f32x4){0.f, 0.f, 0.f, 0.f};

    const unsigned short* f0 = frag;            // batch 0-15 stream
    const unsigned short* f1 = frag + 65536;    // batch 16-31 stream
    const int kbb = (k0 >> 5) + wave * 8;       // this wave's global kb base

    #pragma unroll
    for (int ss = 0; ss < 2; ++ss) {            // 2 scale-groups of 128 k
        i32x4 cd[4];
        #pragma unroll
        for (int st = 0; st < 4; ++st) {
            int row = st * 16 + col;
            int base = (row * 128 + wave * 32 + ss * 16 + g * 4) ^ ((row & 7) << 2);
            cd[st] = *reinterpret_cast<const i32x4*>(&ovl[base]);
        }
        bf16x8 A0[4], A1[4];
        #pragma unroll
        for (int t = 0; t < 4; ++t) {
            int kb = kbb + ss * 4 + t;
            A0[t] = *reinterpret_cast<const bf16x8*>(f0 + ((size_t)kb * 64 + lane) * 8);
            A1[t] = *reinterpret_cast<const bf16x8*>(f1 + ((size_t)kb * 64 + lane) * 8);
        }
        f32x4 ta[4][2];
        #pragma unroll
        for (int st = 0; st < 4; ++st)
            #pragma unroll
            for (int h = 0; h < 2; ++h)
                ta[st][h] = (f32x4){0.f, 0.f, 0.f, 0.f};

        #pragma unroll
        for (int t = 0; t < 4; ++t) {
            #pragma unroll
            for (int st = 0; st < 4; ++st) {
                unsigned code = (unsigned)cd[st][t];
                i32x4 bu;
                bu[0] = (int)tabu[code & 255u];
                bu[1] = (int)tabu[(code >> 8) & 255u];
                bu[2] = (int)tabu[(code >> 16) & 255u];
                bu[3] = (int)tabu[code >> 24];
                bf16x8 bf = __builtin_bit_cast(bf16x8, bu);
                ta[st][0] = __builtin_amdgcn_mfma_f32_16x16x32_bf16(A0[t], bf, ta[st][0], 0, 0, 0);
                ta[st][1] = __builtin_amdgcn_mfma_f32_16x16x32_bf16(A1[t], bf, ta[st][1], 0, 0, 0);
            }
        }
        const int gr = (k0 >> 7) + wave * 2 + ss;
        #pragma unroll
        for (int st = 0; st < 4; ++st) {
            float sc = sct[gr * OUT_F + n0 + st * 16 + col];
            #pragma unroll
            for (int j = 0; j < 4; ++j) {
                acc[st][0][j] = fmaf(sc, ta[st][0][j], acc[st][0][j]);
                acc[st][1][j] = fmaf(sc, ta[st][1][j], acc[st][1][j]);
            }
        }
    }

    // ---- cross-wave K reduction in LDS (reuse ovl), then plain stores ----
    __syncthreads();
    float* red = (float*)ovl;
    #pragma unroll
    for (int st = 0; st < 4; ++st)
        #pragma unroll
        for (int h = 0; h < 2; ++h)
            #pragma unroll
            for (int j = 0; j < 4; ++j)
                red[wave * 2048 + ((st * 2 + h) * 4 + j) * 64 + lane] = acc[st][h][j];
    __syncthreads();

    float* po = part + (size_t)blockIdx.y * OUTSZ;
    #pragma unroll
    for (int q = 0; q < 8; ++q) {
        int i = q * 256 + tid;                   // [0, 2048)
        float s = red[i] + red[2048 + i] + red[4096 + i] + red[6144 + i];
        int l2 = i & 63;
        int j  = (i >> 6) & 3;
        int h  = (i >> 8) & 1;
        int st = i >> 9;
        int b  = h * 16 + (l2 >> 4) * 4 + j;     // batch row (D layout)
        int o  = n0 + st * 16 + (l2 & 15);       // out feature
        po[(size_t)b * OUT_F + o] = s;
    }
}

// ---------------------------------------------------------------------------
// Reduce: out = sum of 4 K-slice partials + bias. grid 1376 x 256 exact.
// ---------------------------------------------------------------------------
__global__ void reduce_kernel(const float* __restrict__ part,
                              const float* __restrict__ bias,
                              float* __restrict__ out) {
    int t = blockIdx.x * 256 + threadIdx.x;
    int o = t % OUT_F;
    out[t] = part[t] + part[OUTSZ + t] + part[2 * OUTSZ + t] + part[3 * OUTSZ + t]
           + bias[o];
}

// ---------------------------------------------------------------------------
extern "C" void kernel_launch(void* const* d_in, const int* in_sizes, int n_in,
                              void* d_out, int out_size, void* d_ws, size_t ws_size,
                              hipStream_t stream) {
    const float* x      = (const float*)d_in[0];
    const int*   packed = (const int*)d_in[1];
    const float* scales = (const float*)d_in[2];
    const float* bias   = (const float*)d_in[3];
    float* out = (float*)d_out;

    char* ws = (char*)d_ws;
    unsigned short* frag = (unsigned short*)ws;
    float* sct  = (float*)(ws + WS_SCT_OFF);
    float* part = (float*)(ws + WS_PART_OFF);

    prelude_kernel<<<1440, 256, 0, stream>>>(x, scales, frag, sct);
    nf4_gemm_kernel<<<dim3(GRID_N, KSPLIT), 256, 0, stream>>>(packed, frag, sct, part);
    reduce_kernel<<<OUTSZ / 256, 256, 0, stream>>>(part, bias, out);
}

// Round 7
// 31.144 us; speedup vs baseline: 1.3605x; 1.0469x over previous
//
#include <hip/hip_runtime.h>
#include <hip/hip_bf16.h>

#define IN_F   4096
#define OUT_F  11008
#define BATCH  32
#define GROUP  128
#define KSPLIT 4
#define KBLK   (IN_F / KSPLIT)    // 1024 k per block = 2 units of 512
#define NTILE  64
#define GRID_N (OUT_F / NTILE)    // 172
#define OUTSZ  (BATCH * OUT_F)    // 352256

typedef __attribute__((ext_vector_type(8))) short  bf16x8;
typedef __attribute__((ext_vector_type(4))) float  f32x4;
typedef __attribute__((ext_vector_type(4))) int    i32x4;

static __device__ __constant__ float NF4_LEVELS[16] = {
    -1.0f, -0.6961928009986877f, -0.5250730514526367f, -0.39491748809814453f,
    -0.28444138169288635f, -0.18477343022823334f, -0.09105003625154495f, 0.0f,
    0.07958029955625534f, 0.16093020141124725f, 0.24611230194568634f,
    0.33791524171829224f, 0.44070982933044434f, 0.5626170039176941f,
    0.7229568362236023f, 1.0f};

// ws layout (bytes): frag 262144 | sct 1409024 | part 5636096
#define WS_SCT_OFF  262144
#define WS_PART_OFF (262144 + 1409024)

// ---------------------------------------------------------------------------
// Prelude: (a) A-fragment streams in MFMA order: frag[st][kb][lane] (16B) =
//   x[st*16+(lane&15)][kb*32+(lane>>4)*8 .. +8) as bf16 -> A-load = 1KB/instr.
// (b) scales transposed: sct[gr][o] = scales[o*32+gr].
// ---------------------------------------------------------------------------
__global__ void prelude_kernel(const float* __restrict__ x,
                               const float* __restrict__ scales,
                               unsigned short* __restrict__ frag,
                               float* __restrict__ sct) {
    const int bid = blockIdx.x, tid = threadIdx.x;
    if (bid < 64) {
        int T  = bid * 256 + tid;
        int st = T >> 13;
        int kb = (T >> 6) & 127;
        int l  = T & 63;
        int row = st * 16 + (l & 15);
        int k0  = kb * 32 + (l >> 4) * 8;
        const float* src = x + (size_t)row * IN_F + k0;
        unsigned w[4];
        #pragma unroll
        for (int e = 0; e < 4; ++e) {
            unsigned lo = __builtin_bit_cast(unsigned short, __float2bfloat16(src[2 * e]));
            unsigned hi = __builtin_bit_cast(unsigned short, __float2bfloat16(src[2 * e + 1]));
            w[e] = lo | (hi << 16);
        }
        i32x4 v = { (int)w[0], (int)w[1], (int)w[2], (int)w[3] };
        *reinterpret_cast<i32x4*>(frag + ((size_t)st * 8192 + kb * 64 + l) * 8) = v;
    } else {
        int B2 = bid - 64;
        int gr = B2 / 43;
        int o  = (B2 % 43) * 256 + tid;
        sct[gr * OUT_F + o] = scales[o * 32 + gr];
    }
}

// ---------------------------------------------------------------------------
// Main: grid (172, 4) = 688 blocks, 256 thr (4 waves), ALL-RESIDENT at 3/CU.
// Block = 64 out-rows x 1024 k as TWO 512-k units, double-buffered LDS.
// Waves split each unit's K 4-ways (128 k = one scale group per wave).
//
// Staging per unit (16 KB codes): wave w stages rows w*16..+15; one row-chunk
//  = 256 int32 = one contiguous 1KB wave-load. Compact 4 int32 -> dword.
//  Source dword j (bits: g=j&3, t=(j>>2)&3, w2=j>>4) stored at
//  d = (j&0x30)|((j&3)<<2)|((j>>2)&3)  (swap g,t fields)
//  addr = u*4096 + (row*64 + d) ^ ((row&7)<<2)   [both-sides swizzle]
//  -> writes: 64 distinct dwords/row, 2-way banks (free)
//  -> reader (wave w, strip st): ds_read_b128 at row*64+w*16+g*4 (^swz)
//     gives k-steps t=0..3; 16 lanes/g-group spread 8 slots = 2-way (free).
// ---------------------------------------------------------------------------
__global__ __launch_bounds__(256, 3) void nf4_gemm_kernel(
        const int* __restrict__ packed,
        const unsigned short* __restrict__ frag,
        const float* __restrict__ sct,
        float* __restrict__ part)
{
    __shared__ unsigned tabu[256];
    __shared__ unsigned lds[8192];   // 32KB: 2 x 4096 code dwords; red alias

    const int tid  = threadIdx.x;
    const int wave = tid >> 6;
    const int lane = tid & 63;
    const int col  = lane & 15;
    const int g    = lane >> 4;

    {
        unsigned lo = __builtin_bit_cast(unsigned short, __float2bfloat16(NF4_LEVELS[tid & 15]));
        unsigned hi = __builtin_bit_cast(unsigned short, __float2bfloat16(NF4_LEVELS[(tid >> 4) & 15]));
        tabu[tid] = lo | (hi << 16);
    }

    const int n0    = blockIdx.x * NTILE;
    const int kint0 = blockIdx.y * 512;          // int32 offset of block k-range
    const int kbB   = blockIdx.y * 32;           // frag kb base
    const int grB   = blockIdx.y * 8;            // scale group base
    const int dperm = (lane & 0x30) | ((lane & 3) << 2) | ((lane >> 2) & 3);

    #define STAGE8_LOAD(u, r, sr)                                             \
        _Pragma("unroll")                                                     \
        for (int ii = 0; ii < 8; ++ii) {                                      \
            int rl = (r) * 8 + ii;                                            \
            sr[ii] = *reinterpret_cast<const i32x4*>(                         \
                packed + (size_t)(n0 + wave * 16 + rl) * (IN_F / 2)           \
                       + kint0 + (u) * 256 + lane * 4);                       \
        }

    #define STAGE8_WRITE(u, r, sr)                                            \
        _Pragma("unroll")                                                     \
        for (int ii = 0; ii < 8; ++ii) {                                      \
            int rl  = (r) * 8 + ii;                                           \
            int row = wave * 16 + rl;                                         \
            unsigned v = ((unsigned)(sr[ii][0] & 255))                        \
                       | ((unsigned)(sr[ii][1] & 255) << 8)                   \
                       | ((unsigned)(sr[ii][2] & 255) << 16)                  \
                       | ((unsigned)(sr[ii][3] & 255) << 24);                 \
            lds[(u) * 4096 + ((row * 64 + dperm) ^ ((row & 7) << 2))] = v;    \
        }

    // prologue: stage unit 0
    {
        i32x4 sr[8];
        STAGE8_LOAD(0, 0, sr) STAGE8_WRITE(0, 0, sr)
        STAGE8_LOAD(0, 1, sr) STAGE8_WRITE(0, 1, sr)
    }
    __syncthreads();

    f32x4 acc[4][2];
    #pragma unroll
    for (int st = 0; st < 4; ++st) {
        acc[st][0] = (f32x4){0.f,0.f,0.f,0.f};
        acc[st][1] = (f32x4){0.f,0.f,0.f,0.f};
    }

    const unsigned short* f0 = frag;
    const unsigned short* f1 = frag + 65536;

    #pragma unroll
    for (int u = 0; u < 2; ++u) {
        i32x4 sr0[8], sr1[8];
        if (u == 0) { STAGE8_LOAD(1, 0, sr0) }     // issue early (T14)

        // codes + scales for this unit
        i32x4 cd[4];
        #pragma unroll
        for (int st = 0; st < 4; ++st) {
            int row  = st * 16 + col;
            int base = u * 4096 + ((row * 64 + wave * 16 + g * 4) ^ ((row & 7) << 2));
            cd[st] = *reinterpret_cast<const i32x4*>(&lds[base]);
        }
        const int gr = grB + u * 4 + wave;
        float sc[4];
        #pragma unroll
        for (int st = 0; st < 4; ++st)
            sc[st] = sct[gr * OUT_F + n0 + st * 16 + col];

        f32x4 t[4][2];
        #pragma unroll
        for (int st = 0; st < 4; ++st) {
            t[st][0] = (f32x4){0.f,0.f,0.f,0.f};
            t[st][1] = (f32x4){0.f,0.f,0.f,0.f};
        }

        // ---- half h=0 (batch 0-15) ----
        {
            bf16x8 A[4];
            #pragma unroll
            for (int tt = 0; tt < 4; ++tt) {
                int kb = kbB + u * 16 + wave * 4 + tt;
                A[tt] = *reinterpret_cast<const bf16x8*>(f0 + ((size_t)kb * 64 + lane) * 8);
            }
            #pragma unroll
            for (int tt = 0; tt < 4; ++tt)
                #pragma unroll
                for (int st = 0; st < 4; ++st) {
                    unsigned code = (unsigned)cd[st][tt];
                    i32x4 bu;
                    bu[0] = (int)tabu[code & 255u];
                    bu[1] = (int)tabu[(code >> 8) & 255u];
                    bu[2] = (int)tabu[(code >> 16) & 255u];
                    bu[3] = (int)tabu[code >> 24];
                    t[st][0] = __builtin_amdgcn_mfma_f32_16x16x32_bf16(
                        A[tt], __builtin_bit_cast(bf16x8, bu), t[st][0], 0, 0, 0);
                }
        }

        if (u == 0) { STAGE8_WRITE(1, 0, sr0) STAGE8_LOAD(1, 1, sr1) }

        // ---- half h=1 (batch 16-31) ----
        {
            bf16x8 A[4];
            #pragma unroll
            for (int tt = 0; tt < 4; ++tt) {
                int kb = kbB + u * 16 + wave * 4 + tt;
                A[tt] = *reinterpret_cast<const bf16x8*>(f1 + ((size_t)kb * 64 + lane) * 8);
            }
            #pragma unroll
            for (int tt = 0; tt < 4; ++tt)
                #pragma unroll
                for (int st = 0; st < 4; ++st) {
                    unsigned code = (unsigned)cd[st][tt];
                    i32x4 bu;
                    bu[0] = (int)tabu[code & 255u];
                    bu[1] = (int)tabu[(code >> 8) & 255u];
                    bu[2] = (int)tabu[(code >> 16) & 255u];
                    bu[3] = (int)tabu[code >> 24];
                    t[st][1] = __builtin_amdgcn_mfma_f32_16x16x32_bf16(
                        A[tt], __builtin_bit_cast(bf16x8, bu), t[st][1], 0, 0, 0);
                }
        }

        if (u == 0) { STAGE8_WRITE(1, 1, sr1) }

        #pragma unroll
        for (int st = 0; st < 4; ++st)
            #pragma unroll
            for (int j = 0; j < 4; ++j) {
                acc[st][0][j] = fmaf(sc[st], t[st][0][j], acc[st][0][j]);
                acc[st][1][j] = fmaf(sc[st], t[st][1][j], acc[st][1][j]);
            }

        __syncthreads();   // unit0: buf1 ready / unit1: codes dead, red safe
    }

    // ---- cross-wave K-reduce in aliased LDS, coalesced partial stores ----
    float* red = (float*)lds;
    #pragma unroll
    for (int st = 0; st < 4; ++st)
        #pragma unroll
        for (int h = 0; h < 2; ++h)
            #pragma unroll
            for (int j = 0; j < 4; ++j)
                red[wave * 2048 + ((st * 2 + h) * 4 + j) * 64 + lane] = acc[st][h][j];
    __syncthreads();

    // thread (wave,lane), q in [0,8): out-row b = q*4+wave (wave-uniform),
    // feature o = n0+lane -> 256B coalesced store per wave.
    float* po = part + (size_t)blockIdx.y * OUTSZ;
    #pragma unroll
    for (int q = 0; q < 8; ++q) {
        int b   = q * 4 + wave;
        int st  = lane >> 4;                 // from o_local = lane
        int c   = lane & 15;
        int h   = b >> 4;
        int g2  = (b >> 2) & 3;
        int j   = b & 3;
        int slot = ((st * 2 + h) * 4 + j) * 64 + g2 * 16 + c;
        float s = red[slot] + red[2048 + slot] + red[4096 + slot] + red[6144 + slot];
        po[(size_t)b * OUT_F + n0 + lane] = s;
    }
}

// ---------------------------------------------------------------------------
__global__ void reduce_kernel(const float* __restrict__ part,
                              const float* __restrict__ bias,
                              float* __restrict__ out) {
    int t = blockIdx.x * 256 + threadIdx.x;
    int o = t % OUT_F;
    out[t] = part[t] + part[OUTSZ + t] + part[2 * OUTSZ + t] + part[3 * OUTSZ + t]
           + bias[o];
}

// ---------------------------------------------------------------------------
extern "C" void kernel_launch(void* const* d_in, const int* in_sizes, int n_in,
                              void* d_out, int out_size, void* d_ws, size_t ws_size,
                              hipStream_t stream) {
    const float* x      = (const float*)d_in[0];
    const int*   packed = (const int*)d_in[1];
    const float* scales = (const float*)d_in[2];
    const float* bias   = (const float*)d_in[3];
    float* out = (float*)d_out;

    char* ws = (char*)d_ws;
    unsigned short* frag = (unsigned short*)ws;
    float* sct  = (float*)(ws + WS_SCT_OFF);
    float* part = (float*)(ws + WS_PART_OFF);

    prelude_kernel<<<1440, 256, 0, stream>>>(x, scales, frag, sct);
    nf4_gemm_kernel<<<dim3(GRID_N, KSPLIT), 256, 0, stream>>>(packed, frag, sct, part);
    reduce_kernel<<<OUTSZ / 256, 256, 0, stream>>>(part, bias, out);
}

// Round 8
// 30.632 us; speedup vs baseline: 1.3832x; 1.0167x over previous
//
#include <hip/hip_runtime.h>
#include <hip/hip_bf16.h>

#define IN_F   4096
#define OUT_F  11008
#define BATCH  32
#define GROUP  128
#define KSPLIT 4
#define KBLK   (IN_F / KSPLIT)    // 1024 k per block = 2 units of 512
#define NTILE  64
#define GRID_N (OUT_F / NTILE)    // 172
#define OUTSZ  (BATCH * OUT_F)    // 352256

typedef __attribute__((ext_vector_type(8))) short  bf16x8;
typedef __attribute__((ext_vector_type(4))) float  f32x4;
typedef __attribute__((ext_vector_type(4))) int    i32x4;

static __device__ __constant__ float NF4_LEVELS[16] = {
    -1.0f, -0.6961928009986877f, -0.5250730514526367f, -0.39491748809814453f,
    -0.28444138169288635f, -0.18477343022823334f, -0.09105003625154495f, 0.0f,
    0.07958029955625534f, 0.16093020141124725f, 0.24611230194568634f,
    0.33791524171829224f, 0.44070982933044434f, 0.5626170039176941f,
    0.7229568362236023f, 1.0f};

// ws layout (bytes): frag 262144 | sct 1409024 | part 5636096
#define WS_SCT_OFF  262144
#define WS_PART_OFF (262144 + 1409024)

// ---------------------------------------------------------------------------
// Prelude: (a) A-fragment streams in MFMA order: frag[st][kb][lane] (16B) =
//   x[st*16+(lane&15)][kb*32+(lane>>4)*8 .. +8) as bf16 -> A-load = 1KB/instr.
// (b) scales transposed: sct[gr][o] = scales[o*32+gr].
// ---------------------------------------------------------------------------
__global__ void prelude_kernel(const float* __restrict__ x,
                               const float* __restrict__ scales,
                               unsigned short* __restrict__ frag,
                               float* __restrict__ sct) {
    const int bid = blockIdx.x, tid = threadIdx.x;
    if (bid < 64) {
        int T  = bid * 256 + tid;
        int st = T >> 13;
        int kb = (T >> 6) & 127;
        int l  = T & 63;
        int row = st * 16 + (l & 15);
        int k0  = kb * 32 + (l >> 4) * 8;
        const float* src = x + (size_t)row * IN_F + k0;
        unsigned w[4];
        #pragma unroll
        for (int e = 0; e < 4; ++e) {
            unsigned lo = __builtin_bit_cast(unsigned short, __float2bfloat16(src[2 * e]));
            unsigned hi = __builtin_bit_cast(unsigned short, __float2bfloat16(src[2 * e + 1]));
            w[e] = lo | (hi << 16);
        }
        i32x4 v = { (int)w[0], (int)w[1], (int)w[2], (int)w[3] };
        *reinterpret_cast<i32x4*>(frag + ((size_t)st * 8192 + kb * 64 + l) * 8) = v;
    } else {
        int B2 = bid - 64;
        int gr = B2 / 43;
        int o  = (B2 % 43) * 256 + tid;
        sct[gr * OUT_F + o] = scales[o * 32 + gr];
    }
}

// ---------------------------------------------------------------------------
// Main: grid (172, 4), 256 thr (4 waves), target 3 blocks/CU (all-resident).
// Block = 64 out-rows x 1024 k as TWO 512-k units, double-buffered LDS.
// KEY CHANGE vs R7: bfrag computed ONCE per (st,tt) and feeds BOTH batch
// halves' MFMAs -> halves the tabu ds_read_b32 traffic (the LDS pipe was
// the serial resource: ~5500 random-indexed lookups/CU ~= 20us).
//
// Staging per unit (16 KB codes): wave w stages rows w*16..+15; one row-chunk
//  = 256 int32 = one contiguous 1KB wave-load. Compact 4 int32 -> dword.
//  Source dword j: d = (j&0x30)|((j&3)<<2)|((j>>2)&3); addr ^= (row&7)<<2.
//  Reader: ds_read_b128 at row*64 + wave*16 + g*4 (^swz) = k-steps t=0..3.
// ---------------------------------------------------------------------------
__global__ __launch_bounds__(256, 3) void nf4_gemm_kernel(
        const int* __restrict__ packed,
        const unsigned short* __restrict__ frag,
        const float* __restrict__ sct,
        float* __restrict__ part)
{
    __shared__ unsigned tabu[256];
    __shared__ unsigned lds[8192];   // 32KB: 2 x 4096 code dwords; red alias

    const int tid  = threadIdx.x;
    const int wave = tid >> 6;
    const int lane = tid & 63;
    const int col  = lane & 15;
    const int g    = lane >> 4;

    {
        unsigned lo = __builtin_bit_cast(unsigned short, __float2bfloat16(NF4_LEVELS[tid & 15]));
        unsigned hi = __builtin_bit_cast(unsigned short, __float2bfloat16(NF4_LEVELS[(tid >> 4) & 15]));
        tabu[tid] = lo | (hi << 16);
    }

    const int n0    = blockIdx.x * NTILE;
    const int kint0 = blockIdx.y * 512;          // int32 offset of block k-range
    const int kbB   = blockIdx.y * 32;           // frag kb base
    const int grB   = blockIdx.y * 8;            // scale group base
    const int dperm = (lane & 0x30) | ((lane & 3) << 2) | ((lane >> 2) & 3);

    #define STAGE8_LOAD(u, r, sr)                                             \
        _Pragma("unroll")                                                     \
        for (int ii = 0; ii < 8; ++ii) {                                      \
            int rl = (r) * 8 + ii;                                            \
            sr[ii] = *reinterpret_cast<const i32x4*>(                         \
                packed + (size_t)(n0 + wave * 16 + rl) * (IN_F / 2)           \
                       + kint0 + (u) * 256 + lane * 4);                       \
        }

    #define STAGE8_WRITE(u, r, sr)                                            \
        _Pragma("unroll")                                                     \
        for (int ii = 0; ii < 8; ++ii) {                                      \
            int rl  = (r) * 8 + ii;                                           \
            int row = wave * 16 + rl;                                         \
            unsigned v = ((unsigned)(sr[ii][0] & 255))                        \
                       | ((unsigned)(sr[ii][1] & 255) << 8)                   \
                       | ((unsigned)(sr[ii][2] & 255) << 16)                  \
                       | ((unsigned)(sr[ii][3] & 255) << 24);                 \
            lds[(u) * 4096 + ((row * 64 + dperm) ^ ((row & 7) << 2))] = v;    \
        }

    // prologue: stage unit 0
    {
        i32x4 sr[8];
        STAGE8_LOAD(0, 0, sr) STAGE8_WRITE(0, 0, sr)
        STAGE8_LOAD(0, 1, sr) STAGE8_WRITE(0, 1, sr)
    }
    __syncthreads();

    f32x4 acc[4][2];
    #pragma unroll
    for (int st = 0; st < 4; ++st) {
        acc[st][0] = (f32x4){0.f,0.f,0.f,0.f};
        acc[st][1] = (f32x4){0.f,0.f,0.f,0.f};
    }

    const unsigned short* f0 = frag;
    const unsigned short* f1 = frag + 65536;

    #pragma unroll
    for (int u = 0; u < 2; ++u) {
        i32x4 sr0[8], sr1[8];
        if (u == 0) { STAGE8_LOAD(1, 0, sr0) }     // issue early (T14)

        // codes + scales for this unit
        i32x4 cd[4];
        #pragma unroll
        for (int st = 0; st < 4; ++st) {
            int row  = st * 16 + col;
            int base = u * 4096 + ((row * 64 + wave * 16 + g * 4) ^ ((row & 7) << 2));
            cd[st] = *reinterpret_cast<const i32x4*>(&lds[base]);
        }
        const int gr = grB + u * 4 + wave;
        float sc[4];
        #pragma unroll
        for (int st = 0; st < 4; ++st)
            sc[st] = sct[gr * OUT_F + n0 + st * 16 + col];

        // A fragments, BOTH batch halves (16 x 1KB contiguous loads)
        bf16x8 A0[4], A1[4];
        #pragma unroll
        for (int tt = 0; tt < 4; ++tt) {
            int kb = kbB + u * 16 + wave * 4 + tt;
            A0[tt] = *reinterpret_cast<const bf16x8*>(f0 + ((size_t)kb * 64 + lane) * 8);
            A1[tt] = *reinterpret_cast<const bf16x8*>(f1 + ((size_t)kb * 64 + lane) * 8);
        }

        f32x4 t[4][2];
        #pragma unroll
        for (int st = 0; st < 4; ++st) {
            t[st][0] = (f32x4){0.f,0.f,0.f,0.f};
            t[st][1] = (f32x4){0.f,0.f,0.f,0.f};
        }

        #pragma unroll
        for (int tt = 0; tt < 4; ++tt) {
            #pragma unroll
            for (int st = 0; st < 4; ++st) {
                unsigned code = (unsigned)cd[st][tt];
                i32x4 bu;                          // bfrag built ONCE...
                bu[0] = (int)tabu[code & 255u];
                bu[1] = (int)tabu[(code >> 8) & 255u];
                bu[2] = (int)tabu[(code >> 16) & 255u];
                bu[3] = (int)tabu[code >> 24];
                bf16x8 bf = __builtin_bit_cast(bf16x8, bu);
                t[st][0] = __builtin_amdgcn_mfma_f32_16x16x32_bf16(A0[tt], bf, t[st][0], 0, 0, 0);
                t[st][1] = __builtin_amdgcn_mfma_f32_16x16x32_bf16(A1[tt], bf, t[st][1], 0, 0, 0);
            }
            if (u == 0 && tt == 1) { STAGE8_WRITE(1, 0, sr0) STAGE8_LOAD(1, 1, sr1) }
        }
        if (u == 0) { STAGE8_WRITE(1, 1, sr1) }

        #pragma unroll
        for (int st = 0; st < 4; ++st)
            #pragma unroll
            for (int j = 0; j < 4; ++j) {
                acc[st][0][j] = fmaf(sc[st], t[st][0][j], acc[st][0][j]);
                acc[st][1][j] = fmaf(sc[st], t[st][1][j], acc[st][1][j]);
            }

        __syncthreads();   // unit0: buf1 ready / unit1: codes dead, red safe
    }

    // ---- cross-wave K-reduce in aliased LDS, coalesced partial stores ----
    float* red = (float*)lds;
    #pragma unroll
    for (int st = 0; st < 4; ++st)
        #pragma unroll
        for (int h = 0; h < 2; ++h)
            #pragma unroll
            for (int j = 0; j < 4; ++j)
                red[wave * 2048 + ((st * 2 + h) * 4 + j) * 64 + lane] = acc[st][h][j];
    __syncthreads();

    // out-row b = q*4+wave (wave-uniform), feature o = n0+lane -> 256B stores.
    float* po = part + (size_t)blockIdx.y * OUTSZ;
    #pragma unroll
    for (int q = 0; q < 8; ++q) {
        int b   = q * 4 + wave;
        int st  = lane >> 4;
        int c   = lane & 15;
        int h   = b >> 4;
        int g2  = (b >> 2) & 3;
        int j   = b & 3;
        int slot = ((st * 2 + h) * 4 + j) * 64 + g2 * 16 + c;
        float s = red[slot] + red[2048 + slot] + red[4096 + slot] + red[6144 + slot];
        po[(size_t)b * OUT_F + n0 + lane] = s;
    }
}

// ---------------------------------------------------------------------------
__global__ void reduce_kernel(const float* __restrict__ part,
                              const float* __restrict__ bias,
                              float* __restrict__ out) {
    int t = blockIdx.x * 256 + threadIdx.x;
    int o = t % OUT_F;
    out[t] = part[t] + part[OUTSZ + t] + part[2 * OUTSZ + t] + part[3 * OUTSZ + t]
           + bias[o];
}

// ---------------------------------------------------------------------------
extern "C" void kernel_launch(void* const* d_in, const int* in_sizes, int n_in,
                              void* d_out, int out_size, void* d_ws, size_t ws_size,
                              hipStream_t stream) {
    const float* x      = (const float*)d_in[0];
    const int*   packed = (const int*)d_in[1];
    const float* scales = (const float*)d_in[2];
    const float* bias   = (const float*)d_in[3];
    float* out = (float*)d_out;

    char* ws = (char*)d_ws;
    unsigned short* frag = (unsigned short*)ws;
    float* sct  = (float*)(ws + WS_SCT_OFF);
    float* part = (float*)(ws + WS_PART_OFF);

    prelude_kernel<<<1440, 256, 0, stream>>>(x, scales, frag, sct);
    nf4_gemm_kernel<<<dim3(GRID_N, KSPLIT), 256, 0, stream>>>(packed, frag, sct, part);
    reduce_kernel<<<OUTSZ / 256, 256, 0, stream>>>(part, bias, out);
}

// Round 9
// 29.870 us; speedup vs baseline: 1.4185x; 1.0255x over previous
//
#include <hip/hip_runtime.h>
#include <hip/hip_bf16.h>

#define IN_F   4096
#define OUT_F  11008
#define BATCH  32
#define GROUP  128
#define KSPLIT 4
#define NTILE  64
#define GRID_N (OUT_F / NTILE)    // 172
#define OUTSZ  (BATCH * OUT_F)    // 352256

typedef __attribute__((ext_vector_type(8))) short  bf16x8;
typedef __attribute__((ext_vector_type(4))) float  f32x4;
typedef __attribute__((ext_vector_type(4))) int    i32x4;
typedef __attribute__((ext_vector_type(4))) float  float4v;

static __device__ __constant__ float NF4_LEVELS[16] = {
    -1.0f, -0.6961928009986877f, -0.5250730514526367f, -0.39491748809814453f,
    -0.28444138169288635f, -0.18477343022823334f, -0.09105003625154495f, 0.0f,
    0.07958029955625534f, 0.16093020141124725f, 0.24611230194568634f,
    0.33791524171829224f, 0.44070982933044434f, 0.5626170039176941f,
    0.7229568362236023f, 1.0f};

// ws layout (bytes): frag 262144 | sct 1409024
#define WS_SCT_OFF  262144

// ---------------------------------------------------------------------------
// Prelude (1784 blocks):
//   bid <   64: A-fragment streams in MFMA order (frag[st][kb][lane], 16B)
//   bid < 1440: scales transpose sct[gr][o] = scales[o*32+gr]
//   bid >=1440: out[b][o] = bias[o]  (base for gemm atomics)
// ---------------------------------------------------------------------------
__global__ void prelude_kernel(const float* __restrict__ x,
                               const float* __restrict__ scales,
                               const float* __restrict__ bias,
                               unsigned short* __restrict__ frag,
                               float* __restrict__ sct,
                               float* __restrict__ out) {
    const int bid = blockIdx.x, tid = threadIdx.x;
    if (bid < 64) {
        int T  = bid * 256 + tid;
        int st = T >> 13;
        int kb = (T >> 6) & 127;
        int l  = T & 63;
        int row = st * 16 + (l & 15);
        int k0  = kb * 32 + (l >> 4) * 8;
        const float* src = x + (size_t)row * IN_F + k0;
        unsigned w[4];
        #pragma unroll
        for (int e = 0; e < 4; ++e) {
            unsigned lo = __builtin_bit_cast(unsigned short, __float2bfloat16(src[2 * e]));
            unsigned hi = __builtin_bit_cast(unsigned short, __float2bfloat16(src[2 * e + 1]));
            w[e] = lo | (hi << 16);
        }
        i32x4 v = { (int)w[0], (int)w[1], (int)w[2], (int)w[3] };
        *reinterpret_cast<i32x4*>(frag + ((size_t)st * 8192 + kb * 64 + l) * 8) = v;
    } else if (bid < 1440) {
        int B2 = bid - 64;               // [0,1376) = 32 groups x 43 blocks
        int gr = B2 / 43;
        int o  = (B2 % 43) * 256 + tid;
        sct[gr * OUT_F + o] = scales[o * 32 + gr];
    } else {
        int t2 = (bid - 1440) * 256 + tid;   // [0, 88064)
        int i  = t2 * 4;
        int o  = i % OUT_F;                  // OUT_F%4==0 -> aligned
        float4v b = *reinterpret_cast<const float4v*>(bias + o);
        *reinterpret_cast<float4v*>(out + i) = b;
    }
}

// ---------------------------------------------------------------------------
// Main: grid (172,4) = 688 blocks, 4 waves, TARGET 4 blocks/CU (all-resident,
// 16 waves/CU for TLP). Block = 64 out-rows x 1024 k as 2 units of 512,
// double-buffered LDS. st-outer/tt-inner loop keeps live regs ~110-125.
// bfrag built once per (st,tt), feeds both batch halves.
//
// Staging per unit (16 KB codes): wave stages rows wave*16..+15; one row-chunk
//  = 256 int32 = one contiguous 1KB wave-load. Compact 4 int32 -> dword.
//  Source dword j: d = (j&0x30)|((j&3)<<2)|((j>>2)&3); addr ^= (row&7)<<2.
//  Reader: ds_read_b128 at row*64 + wave*16 + g*4 (^swz) = k-steps tt=0..3.
// Epilogue: cross-wave LDS reduce, then unsafeAtomicAdd into bias-init'd out.
// ---------------------------------------------------------------------------
__global__ __launch_bounds__(256, 4) void nf4_gemm_kernel(
        const int* __restrict__ packed,
        const unsigned short* __restrict__ frag,
        const float* __restrict__ sct,
        float* __restrict__ out)
{
    __shared__ unsigned tabu[256];
    __shared__ unsigned lds[8192];   // 32KB: 2 x 4096 code dwords; red alias

    const int tid  = threadIdx.x;
    const int wave = tid >> 6;
    const int lane = tid & 63;
    const int col  = lane & 15;
    const int g    = lane >> 4;

    {
        unsigned lo = __builtin_bit_cast(unsigned short, __float2bfloat16(NF4_LEVELS[tid & 15]));
        unsigned hi = __builtin_bit_cast(unsigned short, __float2bfloat16(NF4_LEVELS[(tid >> 4) & 15]));
        tabu[tid] = lo | (hi << 16);
    }

    const int n0    = blockIdx.x * NTILE;
    const int kint0 = blockIdx.y * 512;          // int32 offset of block k-range
    const int kbB   = blockIdx.y * 32;           // frag kb base
    const int grB   = blockIdx.y * 8;            // scale group base
    const int dperm = (lane & 0x30) | ((lane & 3) << 2) | ((lane >> 2) & 3);

    #define STAGE8_LOAD(u, r, sr)                                             \
        _Pragma("unroll")                                                     \
        for (int ii = 0; ii < 8; ++ii) {                                      \
            int rl = (r) * 8 + ii;                                            \
            sr[ii] = *reinterpret_cast<const i32x4*>(                         \
                packed + (size_t)(n0 + wave * 16 + rl) * (IN_F / 2)           \
                       + kint0 + (u) * 256 + lane * 4);                       \
        }

    #define STAGE8_WRITE(u, r, sr)                                            \
        _Pragma("unroll")                                                     \
        for (int ii = 0; ii < 8; ++ii) {                                      \
            int rl  = (r) * 8 + ii;                                           \
            int row = wave * 16 + rl;                                         \
            unsigned v = ((unsigned)(sr[ii][0] & 255))                        \
                       | ((unsigned)(sr[ii][1] & 255) << 8)                   \
                       | ((unsigned)(sr[ii][2] & 255) << 16)                  \
                       | ((unsigned)(sr[ii][3] & 255) << 24);                 \
            lds[(u) * 4096 + ((row * 64 + dperm) ^ ((row & 7) << 2))] = v;    \
        }

    // prologue: stage unit 0
    {
        i32x4 sr[8];
        STAGE8_LOAD(0, 0, sr) STAGE8_WRITE(0, 0, sr)
        STAGE8_LOAD(0, 1, sr) STAGE8_WRITE(0, 1, sr)
    }
    __syncthreads();

    f32x4 acc[4][2];
    #pragma unroll
    for (int st = 0; st < 4; ++st) {
        acc[st][0] = (f32x4){0.f,0.f,0.f,0.f};
        acc[st][1] = (f32x4){0.f,0.f,0.f,0.f};
    }

    const unsigned short* f0 = frag;
    const unsigned short* f1 = frag + 65536;

    #pragma unroll
    for (int u = 0; u < 2; ++u) {
        i32x4 sr[8];                               // single staging buffer
        if (u == 0) { STAGE8_LOAD(1, 0, sr) }      // issue early (T14)

        // A fragments for this unit, both batch halves (8 x 1KB loads)
        bf16x8 A0[4], A1[4];
        #pragma unroll
        for (int tt = 0; tt < 4; ++tt) {
            int kb = kbB + u * 16 + wave * 4 + tt;
            A0[tt] = *reinterpret_cast<const bf16x8*>(f0 + ((size_t)kb * 64 + lane) * 8);
            A1[tt] = *reinterpret_cast<const bf16x8*>(f1 + ((size_t)kb * 64 + lane) * 8);
        }

        const int gr = grB + u * 4 + wave;

        #pragma unroll
        for (int st = 0; st < 4; ++st) {
            int row  = st * 16 + col;
            i32x4 cdv = *reinterpret_cast<const i32x4*>(
                &lds[u * 4096 + ((row * 64 + wave * 16 + g * 4) ^ ((row & 7) << 2))]);
            float sc = sct[gr * OUT_F + n0 + st * 16 + col];

            f32x4 t0 = (f32x4){0.f,0.f,0.f,0.f};
            f32x4 t1 = (f32x4){0.f,0.f,0.f,0.f};
            #pragma unroll
            for (int tt = 0; tt < 4; ++tt) {
                unsigned code = (unsigned)cdv[tt];
                i32x4 bu;                          // bfrag once, both halves
                bu[0] = (int)tabu[code & 255u];
                bu[1] = (int)tabu[(code >> 8) & 255u];
                bu[2] = (int)tabu[(code >> 16) & 255u];
                bu[3] = (int)tabu[code >> 24];
                bf16x8 bf = __builtin_bit_cast(bf16x8, bu);
                t0 = __builtin_amdgcn_mfma_f32_16x16x32_bf16(A0[tt], bf, t0, 0, 0, 0);
                t1 = __builtin_amdgcn_mfma_f32_16x16x32_bf16(A1[tt], bf, t1, 0, 0, 0);
            }
            #pragma unroll
            for (int j = 0; j < 4; ++j) {
                acc[st][0][j] = fmaf(sc, t0[j], acc[st][0][j]);
                acc[st][1][j] = fmaf(sc, t1[j], acc[st][1][j]);
            }
            if (u == 0 && st == 1) { STAGE8_WRITE(1, 0, sr) STAGE8_LOAD(1, 1, sr) }
        }
        if (u == 0) { STAGE8_WRITE(1, 1, sr) }

        __syncthreads();   // u0: buf1 ready / u1: codes dead, red alias safe
    }

    // ---- cross-wave K-reduce in aliased LDS, then atomic accumulate ----
    float* red = (float*)lds;
    #pragma unroll
    for (int st = 0; st < 4; ++st)
        #pragma unroll
        for (int h = 0; h < 2; ++h)
            #pragma unroll
            for (int j = 0; j < 4; ++j)
                red[wave * 2048 + ((st * 2 + h) * 4 + j) * 64 + lane] = acc[st][h][j];
    __syncthreads();

    // out-row b = q*4+wave (wave-uniform), feature o = n0+lane -> 256B/wave
    #pragma unroll
    for (int q = 0; q < 8; ++q) {
        int b   = q * 4 + wave;
        int st  = lane >> 4;
        int c   = lane & 15;
        int h   = b >> 4;
        int g2  = (b >> 2) & 3;
        int j   = b & 3;
        int slot = ((st * 2 + h) * 4 + j) * 64 + g2 * 16 + c;
        float s = red[slot] + red[2048 + slot] + red[4096 + slot] + red[6144 + slot];
        unsafeAtomicAdd(out + (size_t)b * OUT_F + n0 + lane, s);
    }
}

// ---------------------------------------------------------------------------
extern "C" void kernel_launch(void* const* d_in, const int* in_sizes, int n_in,
                              void* d_out, int out_size, void* d_ws, size_t ws_size,
                              hipStream_t stream) {
    const float* x      = (const float*)d_in[0];
    const int*   packed = (const int*)d_in[1];
    const float* scales = (const float*)d_in[2];
    const float* bias   = (const float*)d_in[3];
    float* out = (float*)d_out;

    char* ws = (char*)d_ws;
    unsigned short* frag = (unsigned short*)ws;
    float* sct = (float*)(ws + WS_SCT_OFF);

    prelude_kernel<<<1784, 256, 0, stream>>>(x, scales, bias, frag, sct, out);
    nf4_gemm_kernel<<<dim3(GRID_N, KSPLIT), 256, 0, stream>>>(packed, frag, sct, out);
}